// Round 3
// baseline (863.957 us; speedup 1.0000x reference)
//
#include <hip/hip_runtime.h>
#include <stdint.h>
#include <stddef.h>

// ---------- types ----------
typedef __attribute__((ext_vector_type(8))) short bf16x8;  // 8 bf16 (4 VGPRs)
typedef __attribute__((ext_vector_type(4))) short bf16x4;
typedef __attribute__((ext_vector_type(4))) float f32x4;

typedef const __attribute__((address_space(1))) uint32_t gas_u32;
typedef __attribute__((address_space(3))) uint32_t las_u32;

__device__ __forceinline__ short f2bf(float f) {
  union { float f; uint32_t u; } c; c.f = f;
  uint32_t u = c.u;
  u += 0x7fffu + ((u >> 16) & 1u);   // RNE
  return (short)(u >> 16);
}

// ---------- fused fp32 -> bf16 convert over up to 7 segments (one launch) ----------
struct CvtArgs {
  const float* s[7];
  short* d[7];
  long cum[8];   // cum[0]=0, cum[k+1]=cum[k]+n_k; all n_k % 4 == 0
};

__global__ void k_cvt_multi(CvtArgs a) {
  long i = ((long)blockIdx.x * 256 + threadIdx.x) * 4;
  if (i >= a.cum[7]) return;
  int g = 0;
  while (i >= a.cum[g + 1]) ++g;   // <=7 iters, wave-coherent except at boundaries
  long o = i - a.cum[g];
  float4 v = *(const float4*)(a.s[g] + o);
  bf16x4 ov = { f2bf(v.x), f2bf(v.y), f2bf(v.z), f2bf(v.w) };
  *(bf16x4*)(a.d[g] + o) = ov;
}

// gather rows [row0, row0+rpb) of each batch's (93,2048) context into packed (8*rpb,2048) bf16
__global__ void k_cvt_ctx(const float* __restrict__ ctx, short* __restrict__ dst,
                          int rpb, int row0) {
  long total = 8L * rpb * 2048;
  long i = ((long)blockIdx.x * 256 + threadIdx.x) * 4;
  if (i >= total) return;
  int c = (int)(i & 2047);
  long rs = i >> 11;
  int b = (int)(rs / rpb);
  int s = (int)(rs - (long)b * rpb);
  const float* sp = ctx + ((long)(b * 93 + row0 + s) * 2048 + c);
  float4 v = *(const float4*)sp;
  bf16x4 o = { f2bf(v.x), f2bf(v.y), f2bf(v.z), f2bf(v.w) };
  *(bf16x4*)(dst + i) = o;
}

// ---------- GEMM 256x256, BK=32, 8 waves, 4-deep counted-vmcnt pipeline ----------
// C[M,N] = A[M,K] * B[N,K]^T (row-major bf16, fp32 acc). N%256==0, K%128==0;
// M arbitrary (staging rows clamped, epilogue guarded by Mreal).
//
// Pipeline (T3+T4): 4 step-buffers of (A 256x32 + B 256x32) = 32 KB each,
// 128 KiB LDS total. Steady state: issue step s+3's 4 global_load_lds, then
// s_waitcnt vmcnt(12) (waits ONLY step s's 4 loads; 12 stay in flight across
// the raw s_barrier), ds_read + 32 MFMA, end barrier (frees buf for s+4).
// vmcnt never drains to 0 in the main loop (epilogue: 8 -> 4 -> 0).
//
// LDS swizzle (proven 0-conflict): 32-short rows = 4 16B chunks; global chunk c
// of row r stored at slot c ^ ((r>>1)&3); reader swz = (q4 ^ ((r16>>1)&3))*8.
// Staging writes are lane-contiguous (global_load_lds constraint); the source
// chunk is pre-permuted (both-sides rule).
//
// Optional second problem appended along blockIdx.y (by >= split_by): used to
// merge the txt/img KV projections into one launch.
// MODE 0: bf16 head-permuted store: out[((grp*160 + b*20 + h%20)*SPB + s)*64 + d]
// MODE 1: fp32 row-major + bias[n]
template <int MODE>
__global__ __launch_bounds__(512, 2)
void k_gemm256(const short* __restrict__ A, const short* __restrict__ Bm,
               void* __restrict__ out, const float* __restrict__ bias,
               int Mreal, int N, int K, int SPB,
               const short* __restrict__ A2, const short* __restrict__ B2,
               void* __restrict__ out2, int Mreal2, int SPB2, int split_by) {
  __shared__ __align__(16) short As[4][256 * 32];
  __shared__ __align__(16) short Bs[4][256 * 32];
  const int t = threadIdx.x;
  const int lane = t & 63;
  const int wave = t >> 6;
  const int q4 = lane >> 4, r16 = lane & 15;
  const int wm = (wave >> 2) * 128;   // 2 M-wave rows of 128
  const int wn = (wave & 3) * 64;     // 4 N-wave cols of 64

  // XCD-aware contiguous remap (requires nwg % 8 == 0: 640 / 640 / 40 all ok)
  const int nwg = gridDim.x * gridDim.y;
  const int lin = blockIdx.y * gridDim.x + blockIdx.x;
  const int cpx = nwg >> 3;
  const int wg = (lin & 7) * cpx + (lin >> 3);
  const int bx = wg % gridDim.x;
  int by = wg / gridDim.x;

  // problem select (merged-launch support)
  const short* Ap = A; const short* Bp = Bm; void* op = out;
  int Mr = Mreal, SP = SPB;
  if (by >= split_by) { Ap = A2; Bp = B2; op = out2; Mr = Mreal2; SP = SPB2; by -= split_by; }
  const int m0 = by * 256, n0 = bx * 256;

  f32x4 zero = {0.f, 0.f, 0.f, 0.f};
  f32x4 acc[8][4];
#pragma unroll
  for (int i = 0; i < 8; ++i)
#pragma unroll
    for (int j = 0; j < 4; ++j) acc[i][j] = zero;

  // staging: per step, thread t owns chunks {t, t+512} of A and of B.
  // chunk p -> row p>>2 (0..255), slot p&3; source global chunk = slot ^ ((row>>1)&3).
  const int srow = t >> 2;                       // 0..127
  const int csrc = (t & 3) ^ ((srow >> 1) & 3);  // same for row and row+128
  int ra0 = m0 + srow;        if (ra0 >= Mr) ra0 = Mr - 1;
  int ra1 = m0 + 128 + srow;  if (ra1 >= Mr) ra1 = Mr - 1;
  const short* gA0 = Ap + (size_t)ra0 * K + csrc * 8;
  const short* gA1 = Ap + (size_t)ra1 * K + csrc * 8;
  const short* gB0 = Bp + (size_t)(n0 + srow) * K + csrc * 8;
  const short* gB1 = Bp + (size_t)(n0 + 128 + srow) * K + csrc * 8;

  const int swz = (q4 ^ ((r16 >> 1) & 3)) * 8;

  auto stage = [&](int sb, int k0) {
    short* as = &As[0][0] + sb * (256 * 32);
    short* bs = &Bs[0][0] + sb * (256 * 32);
    __builtin_amdgcn_global_load_lds((gas_u32*)(gA0 + k0), (las_u32*)(as + t * 8), 16, 0, 0);
    __builtin_amdgcn_global_load_lds((gas_u32*)(gA1 + k0), (las_u32*)(as + (t + 512) * 8), 16, 0, 0);
    __builtin_amdgcn_global_load_lds((gas_u32*)(gB0 + k0), (las_u32*)(bs + t * 8), 16, 0, 0);
    __builtin_amdgcn_global_load_lds((gas_u32*)(gB1 + k0), (las_u32*)(bs + (t + 512) * 8), 16, 0, 0);
  };

  auto dostep = [&](int sb) {
    const short* as = &As[0][0] + sb * (256 * 32);
    const short* bs = &Bs[0][0] + sb * (256 * 32);
    bf16x8 av[8], bv[4];
#pragma unroll
    for (int i = 0; i < 8; ++i)
      av[i] = *(const bf16x8*)(as + (wm + i * 16 + r16) * 32 + swz);
#pragma unroll
    for (int j = 0; j < 4; ++j)
      bv[j] = *(const bf16x8*)(bs + (wn + j * 16 + r16) * 32 + swz);
    __builtin_amdgcn_s_setprio(1);
#pragma unroll
    for (int i = 0; i < 8; ++i)
#pragma unroll
      for (int j = 0; j < 4; ++j)
        acc[i][j] = __builtin_amdgcn_mfma_f32_16x16x32_bf16(av[i], bv[j], acc[i][j], 0, 0, 0);
    __builtin_amdgcn_s_setprio(0);
    __builtin_amdgcn_s_barrier();   // all waves done reading buf sb -> free for s+4
  };

  const int NS = K >> 5;   // K-steps of 32 (>= 4; 40 / 64 here)

  // prologue: 3 steps in flight (12 loads)
  stage(0, 0);
  stage(1, 32);
  stage(2, 64);

  for (int s = 0; s < NS - 3; ++s) {
    stage((s + 3) & 3, (s + 3) * 32);
    asm volatile("s_waitcnt vmcnt(12)" ::: "memory");   // step s's 4 loads done; 12 in flight
    __builtin_amdgcn_s_barrier();                        // everyone's step-s loads visible
    dostep(s & 3);
  }
  asm volatile("s_waitcnt vmcnt(8)" ::: "memory");
  __builtin_amdgcn_s_barrier();
  dostep((NS - 3) & 3);
  asm volatile("s_waitcnt vmcnt(4)" ::: "memory");
  __builtin_amdgcn_s_barrier();
  dostep((NS - 2) & 3);
  asm volatile("s_waitcnt vmcnt(0)" ::: "memory");
  __builtin_amdgcn_s_barrier();
  dostep((NS - 1) & 3);

  // epilogue. D layout (verified): row = q4*4 + rr, col = r16 within each 16x16 tile.
  if (MODE == 0) {
    short* O = (short*)op;
#pragma unroll
    for (int i = 0; i < 8; ++i) {
#pragma unroll
      for (int rr = 0; rr < 4; ++rr) {
        int m = m0 + wm + i * 16 + q4 * 4 + rr;
        if (m < Mr) {
          int bb, ss;
          if (SP == 4096) { bb = m >> 12; ss = m & 4095; }
          else            { bb = m / SP; ss = m - bb * SP; }
#pragma unroll
          for (int j = 0; j < 4; ++j) {
            int n = n0 + wn + j * 16 + r16;
            int h = n >> 6, d = n & 63;
            int grp = (h >= 20) ? 1 : 0;   // K vs V half when N==2560
            int hl = h - grp * 20;
            O[(((size_t)(grp * 160 + bb * 20 + hl)) * SP + ss) * 64 + d] = f2bf(acc[i][j][rr]);
          }
        }
      }
    }
  } else {
    float* O = (float*)op;
#pragma unroll
    for (int i = 0; i < 8; ++i) {
#pragma unroll
      for (int rr = 0; rr < 4; ++rr) {
        int m = m0 + wm + i * 16 + q4 * 4 + rr;
        if (m < Mr) {
#pragma unroll
          for (int j = 0; j < 4; ++j) {
            int n = n0 + wn + j * 16 + r16;
            O[(size_t)m * N + n] = acc[i][j][rr] + bias[n];
          }
        }
      }
    }
  }
}

// ---------- fused dual attention: out = softmax(QKt^T/8)Vt + scale*softmax(QKi^T/8)Vi ----------
// Q,K,V in (b,h,s,64) bf16. Keys padded: rows 0..76 txt, 77..79 zero (masked), 80..95 img.
__global__ __launch_bounds__(256)
void k_attn(const short* __restrict__ qb, const short* __restrict__ kb,
            const short* __restrict__ vb, const short* __restrict__ kib,
            const short* __restrict__ vib, const float* __restrict__ scale_p,
            short* __restrict__ out) {
  constexpr int KS = 72;    // Ks row stride (shorts): 144B -> 2-way bank alias (free)
  constexpr int PS = 104;   // Vt/P row stride: 208B -> 2-way alias (free), 16B aligned
  __shared__ __align__(16) short Ks[96 * KS];
  __shared__ __align__(16) short Vt[64 * PS];      // transposed: Vt[d][key]
  __shared__ __align__(16) short Pp[4][16 * PS];   // per-wave P (A-layout staging)
  const int t = threadIdx.x, lane = t & 63, wave = t >> 6;
  const int q4 = lane >> 4, r16 = lane & 15;
  const int b = blockIdx.z, h = blockIdx.y, qt = blockIdx.x;
  const int bh = b * 20 + h;
  const short* kt = kb + (size_t)bh * 77 * 64;
  const short* vt = vb + (size_t)bh * 77 * 64;
  const short* ki = kib + (size_t)bh * 16 * 64;
  const short* vi = vib + (size_t)bh * 16 * 64;

  for (int c = t; c < 96 * 8; c += 256) {
    int row = c >> 3, o = (c & 7) * 8;
    uint4 val = {0u, 0u, 0u, 0u};
    if (row < 77)       val = *(const uint4*)(kt + row * 64 + o);
    else if (row >= 80) val = *(const uint4*)(ki + (row - 80) * 64 + o);
    *(uint4*)(Ks + row * KS + o) = val;
  }
  for (int i = t; i < 96 * 64; i += 256) {
    int key = i >> 6, d = i & 63;
    short v = 0;
    if (key < 77)       v = vt[key * 64 + d];
    else if (key >= 80) v = vi[(key - 80) * 64 + d];
    Vt[d * PS + key] = v;
  }
  __syncthreads();

  const int s0 = qt * 64 + wave * 16;
  const short* qp = qb + ((size_t)bh * 4096 + s0) * 64;
  bf16x8 qf[2];
#pragma unroll
  for (int kc = 0; kc < 2; ++kc)
    qf[kc] = *(const bf16x8*)(qp + r16 * 64 + kc * 32 + q4 * 8);

  f32x4 zero = {0.f, 0.f, 0.f, 0.f};
  f32x4 lg[6];
#pragma unroll
  for (int nt = 0; nt < 6; ++nt) {
    lg[nt] = zero;
#pragma unroll
    for (int kc = 0; kc < 2; ++kc) {
      bf16x8 kf = *(const bf16x8*)(Ks + (nt * 16 + r16) * KS + kc * 32 + q4 * 8);
      lg[nt] = __builtin_amdgcn_mfma_f32_16x16x32_bf16(qf[kc], kf, lg[nt], 0, 0, 0);
    }
  }

  const float sm = 0.125f;
  const float scl = scale_p[0];
#pragma unroll
  for (int nt = 0; nt < 6; ++nt)
#pragma unroll
    for (int rr = 0; rr < 4; ++rr) lg[nt][rr] *= sm;
  if (r16 >= 13) {
#pragma unroll
    for (int rr = 0; rr < 4; ++rr) lg[4][rr] = -1e30f;
  }

#pragma unroll
  for (int rr = 0; rr < 4; ++rr) {
    float mx = -1e30f;
#pragma unroll
    for (int nt = 0; nt < 5; ++nt) mx = fmaxf(mx, lg[nt][rr]);
#pragma unroll
    for (int o = 1; o < 16; o <<= 1) mx = fmaxf(mx, __shfl_xor(mx, o, 64));
    float s = 0.f;
#pragma unroll
    for (int nt = 0; nt < 5; ++nt) {
      float p = __expf(lg[nt][rr] - mx);
      lg[nt][rr] = p; s += p;
    }
#pragma unroll
    for (int o = 1; o < 16; o <<= 1) s += __shfl_xor(s, o, 64);
    float inv = 1.f / s;
#pragma unroll
    for (int nt = 0; nt < 5; ++nt) lg[nt][rr] *= inv;

    float mi = lg[5][rr];
#pragma unroll
    for (int o = 1; o < 16; o <<= 1) mi = fmaxf(mi, __shfl_xor(mi, o, 64));
    float pi = __expf(lg[5][rr] - mi);
    float si = pi;
#pragma unroll
    for (int o = 1; o < 16; o <<= 1) si += __shfl_xor(si, o, 64);
    lg[5][rr] = pi * (scl / si);
  }

  short* pw = &Pp[wave][0];
#pragma unroll
  for (int nt = 0; nt < 6; ++nt)
#pragma unroll
    for (int rr = 0; rr < 4; ++rr)
      pw[(q4 * 4 + rr) * PS + nt * 16 + r16] = f2bf(lg[nt][rr]);

  f32x4 oc[4];
#pragma unroll
  for (int dt = 0; dt < 4; ++dt) {
    oc[dt] = zero;
#pragma unroll
    for (int kc = 0; kc < 3; ++kc) {
      bf16x8 pf = *(const bf16x8*)(pw + r16 * PS + kc * 32 + q4 * 8);
      bf16x8 vf = *(const bf16x8*)(Vt + (dt * 16 + r16) * PS + kc * 32 + q4 * 8);
      oc[dt] = __builtin_amdgcn_mfma_f32_16x16x32_bf16(pf, vf, oc[dt], 0, 0, 0);
    }
  }

#pragma unroll
  for (int dt = 0; dt < 4; ++dt)
#pragma unroll
    for (int rr = 0; rr < 4; ++rr) {
      int m = s0 + q4 * 4 + rr;
      int d = dt * 16 + r16;
      out[((size_t)b * 4096 + m) * 1280 + h * 64 + d] = f2bf(oc[dt][rr]);
    }
}

// ---------- launch ----------
extern "C" void kernel_launch(void* const* d_in, const int* in_sizes, int n_in,
                              void* d_out, int out_size, void* d_ws, size_t ws_size,
                              hipStream_t stream) {
  const float* x    = (const float*)d_in[0];
  const float* ctx  = (const float*)d_in[1];
  const float* scal = (const float*)d_in[2];
  // d_in[3] = num_img_token (fixed 16; eos = 77)
  const float* Wq   = (const float*)d_in[4];
  const float* Wk   = (const float*)d_in[5];
  const float* Wv   = (const float*)d_in[6];
  const float* Wkip = (const float*)d_in[7];
  const float* Wvip = (const float*)d_in[8];
  const float* Wout = (const float*)d_in[9];
  const float* bout = (const float*)d_in[10];
  float* out = (float*)d_out;

  char* ws = (char*)d_ws;
  size_t off = 0;
  auto alloc = [&](size_t elems) -> short* {
    short* p = (short*)(ws + off);
    off += (elems * 2 + 255) & ~(size_t)255;
    return p;
  };
  short* xb    = alloc(32768UL * 1280);   // also reused as attn output (x dead after Q proj)
  short* txtb  = alloc(616UL * 2048);
  short* imgb  = alloc(128UL * 2048);
  short* Wqb   = alloc(1280UL * 1280);
  short* Wkvb  = alloc(2UL * 1280 * 2048);
  short* Wkvip = alloc(2UL * 1280 * 2048);
  short* Woutb = alloc(1280UL * 1280);
  short* qb    = alloc(32768UL * 1280);   // (b,h,4096,64)
  short* kb    = alloc(2UL * 160 * 77 * 64);
  short* kib   = alloc(2UL * 160 * 16 * 64);
  short* vb    = kb  + 160UL * 77 * 64;
  short* vib   = kib + 160UL * 16 * 64;
  short* attnb = xb;

  // one fused cvt launch for x + all 6 weight matrices
  {
    CvtArgs a;
    const float* srcs[7] = { x, Wq, Wk, Wv, Wkip, Wvip, Wout };
    short* dsts[7] = { xb, Wqb, Wkvb, Wkvb + 1280L * 2048, Wkvip,
                       Wkvip + 1280L * 2048, Woutb };
    long ns[7] = { 32768L * 1280, 1280L * 1280, 1280L * 2048, 1280L * 2048,
                   1280L * 2048, 1280L * 2048, 1280L * 1280 };
    long c = 0;
    for (int k = 0; k < 7; ++k) { a.s[k] = srcs[k]; a.d[k] = dsts[k]; a.cum[k] = c; c += ns[k]; }
    a.cum[7] = c;
    int blocks = (int)((c / 4 + 255) / 256);
    k_cvt_multi<<<blocks, 256, 0, stream>>>(a);
  }
  {
    long n1 = 8L * 77 * 2048;
    k_cvt_ctx<<<(int)((n1 / 4 + 255) / 256), 256, 0, stream>>>(ctx, txtb, 77, 0);
    long n2 = 8L * 16 * 2048;
    k_cvt_ctx<<<(int)((n2 / 4 + 255) / 256), 256, 0, stream>>>(ctx, imgb, 16, 77);
  }

  // Q projection: M=32768, N=1280, K=1280
  { dim3 g(5, 128);
    k_gemm256<0><<<g, 512, 0, stream>>>(xb, Wqb, qb, nullptr, 32768, 1280, 1280, 4096,
                                        nullptr, nullptr, nullptr, 0, 0, 1 << 20); }
  // merged KV projections: by 0..2 = txt (M=616), by 3 = img (M=128); N=2560, K=2048
  { dim3 g(10, 4);
    k_gemm256<0><<<g, 512, 0, stream>>>(txtb, Wkvb, kb, nullptr, 616, 2560, 2048, 77,
                                        imgb, Wkvip, kib, 128, 16, 3); }
  { dim3 g(64, 20, 8);
    k_attn<<<g, 256, 0, stream>>>(qb, kb, vb, kib, vib, scal, attnb); }
  // output projection: M=32768, N=1280, K=1280, fp32 + bias
  { dim3 g(5, 128);
    k_gemm256<1><<<g, 512, 0, stream>>>(attnb, Woutb, out, bout, 32768, 1280, 1280, 1,
                                        nullptr, nullptr, nullptr, 0, 0, 1 << 20); }
}